// Round 13
// baseline (25.207 us; speedup 1.0000x reference)
//
#include <hip/hip_runtime.h>

#define NRAYS 32768
#define THRS  5e-5f

typedef float f32x4 __attribute__((ext_vector_type(4)));
typedef short s16x8 __attribute__((ext_vector_type(8)));

// ---- LDS byte map (105616 B total, 1 block/CU) ----
#define WB(s,ct,kb) ((((s)*8+(ct))*4+(kb))*1024)
#define T1B  98304   // float4[128] = (W1x,W1y,W1z,b1)
#define B2B  100352  // float[128]
#define W3B  100864  // float[128]
#define B3B  101376  // float (padded to 16)
#define PXB  101392  // float[256] compacted point x
#define PYB  102416
#define PZB  103440
#define SDFB 104464  // float[256]
#define CNTB 105488  // int[32] rotating compaction counters (zeroed once)
#define LDSZ 105616

// Cheap softplus: max(x,0) + ln2 * log2(1 + 2^(-|x|*log2e)).
__device__ __forceinline__ float softplus_f(float x){
  const float L2E = 1.44269504088896340f;
  const float LN2 = 0.69314718055994531f;
  float y = __builtin_amdgcn_exp2f(-fabsf(x) * L2E);
  float l = __builtin_amdgcn_logf(1.0f + y);      // log2(1+y)
  return fmaf(LN2, l, fmaxf(x, 0.0f));
}

__device__ __forceinline__ float bf16tof(unsigned short h){
  return __uint_as_float(((unsigned int)h) << 16);
}
// Truncation 3-way bf16 split: exact for fp32 (3x8 = 24 mantissa bits).
__device__ __forceinline__ void split3(float h, unsigned short& a0,
                                       unsigned short& a1, unsigned short& a2){
  a0 = (unsigned short)(__float_as_uint(h) >> 16);
  const float r1 = h - bf16tof(a0);
  a1 = (unsigned short)(__float_as_uint(r1) >> 16);
  const float r2 = r1 - bf16tof(a1);
  a2 = (unsigned short)(__float_as_uint(r2) >> 16);
}

// Batched MLP eval over compacted rows 0..nw*32-1. Waves >= nw skip all
// work (B-read traffic scales with nw). Ends with a barrier (SDFB ready).
__device__ __forceinline__ void eval_blockN(unsigned char* sm, int t, int nw){
  const int lane = t & 63;
  const int wave = t >> 6;          // 0..7
  const int l15  = lane & 15;
  const int lhi  = lane >> 4;

  if (wave < nw){
    float prx[2], pry[2], prz[2];
#pragma unroll
    for (int mt = 0; mt < 2; ++mt){
      const int row = wave*32 + mt*16 + l15;
      prx[mt] = ((const float*)(sm+PXB))[row];
      pry[mt] = ((const float*)(sm+PYB))[row];
      prz[mt] = ((const float*)(sm+PZB))[row];
    }

    f32x4 acc[2][8];
#pragma unroll
    for (int mt = 0; mt < 2; ++mt)
#pragma unroll
      for (int ct = 0; ct < 8; ++ct){
        f32x4 zv = {0.f,0.f,0.f,0.f};
        acc[mt][ct] = zv;
      }

#pragma unroll
    for (int kb = 0; kb < 4; ++kb){
      s16x8 A0[2], A1[2], A2[2];
#pragma unroll
      for (int u = 0; u < 8; ++u){
        const int k = kb*32 + lhi*8 + u;          // per-lane k
        const float4 t1 = ((const float4*)(sm+T1B))[k];
#pragma unroll
        for (int mt = 0; mt < 2; ++mt){
          const float pre = fmaf(prx[mt], t1.x,
                            fmaf(pry[mt], t1.y,
                            fmaf(prz[mt], t1.z, t1.w)));
          const float h = softplus_f(pre);
          unsigned short uh, um, ul;
          split3(h, uh, um, ul);
          A0[mt][u] = (short)uh; A1[mt][u] = (short)um; A2[mt][u] = (short)ul;
        }
      }
#pragma unroll
      for (int ct = 0; ct < 8; ++ct){
        const s16x8 B0  = *(const s16x8*)(sm + WB(0,ct,kb) + lane*16);
        const s16x8 B1  = *(const s16x8*)(sm + WB(1,ct,kb) + lane*16);
        const s16x8 B2w = *(const s16x8*)(sm + WB(2,ct,kb) + lane*16);
#pragma unroll
        for (int mt = 0; mt < 2; ++mt){
          f32x4 a = acc[mt][ct];
          a = __builtin_amdgcn_mfma_f32_16x16x32_bf16(A0[mt], B0,  a, 0,0,0);
          a = __builtin_amdgcn_mfma_f32_16x16x32_bf16(A0[mt], B1,  a, 0,0,0);
          a = __builtin_amdgcn_mfma_f32_16x16x32_bf16(A1[mt], B0,  a, 0,0,0);
          a = __builtin_amdgcn_mfma_f32_16x16x32_bf16(A0[mt], B2w, a, 0,0,0);
          a = __builtin_amdgcn_mfma_f32_16x16x32_bf16(A1[mt], B1,  a, 0,0,0);
          a = __builtin_amdgcn_mfma_f32_16x16x32_bf16(A2[mt], B0,  a, 0,0,0);
          acc[mt][ct] = a;
        }
      }
    }

    float b2v[8], w3v[8];
#pragma unroll
    for (int ct = 0; ct < 8; ++ct){
      const int col = ct*16 + l15;
      b2v[ct] = ((const float*)(sm+B2B))[col];
      w3v[ct] = ((const float*)(sm+W3B))[col];
    }
#pragma unroll
    for (int mt = 0; mt < 2; ++mt){
#pragma unroll
      for (int i = 0; i < 4; ++i){
        // C layout (m89-verified): row = wave*32+mt*16+lhi*4+i, col = ct*16+l15
        float v = 0.f;
#pragma unroll
        for (int ct = 0; ct < 8; ++ct)
          v = fmaf(softplus_f(acc[mt][ct][i] + b2v[ct]), w3v[ct], v);
        v += __shfl_xor(v, 1);
        v += __shfl_xor(v, 2);
        v += __shfl_xor(v, 4);
        v += __shfl_xor(v, 8);                   // reduce over 16 col-lanes
        if (l15 == 0)
          ((float*)(sm+SDFB))[wave*32 + mt*16 + lhi*4 + i] = v;
      }
    }
  }
  __syncthreads();                               // SDFB ready
}

// Compact (per-wave LDS atomicAdd, rotating counter slot) + eval + gather.
__device__ __forceinline__ float do_eval(unsigned char* sm, int t, bool flag,
                                         float px, float py, float pz,
                                         float prev, int evalIdx){
  const int lane = t & 63;
  int* cnt = (int*)(sm + CNTB);
  const unsigned long long bal = __ballot(flag);
  const int pc = __popcll(bal);
  int base = 0;
  if (pc){                                       // wave-uniform condition
    int old = 0;
    if (lane == 0) old = atomicAdd(&cnt[evalIdx], pc);
    base = __shfl(old, 0);                       // all lanes execute
  }
  const int slot = base + __popcll(bal & ((1ULL << lane) - 1ULL));
  if (flag){
    ((float*)(sm+PXB))[slot] = px;
    ((float*)(sm+PYB))[slot] = py;
    ((float*)(sm+PZB))[slot] = pz;
  }
  __syncthreads();                               // points + counter visible
  const int total = cnt[evalIdx];                // uniform
  if (total == 0) return prev;                   // block-uniform
  eval_blockN(sm, t, (total + 31) >> 5);         // ends with barrier
  float r = prev;
  if (flag)
    r = ((const float*)(sm+SDFB))[slot] + *((const float*)(sm+B3B));
  return r;
}

// Speculative 2-probe eval (bisection probes are oblivious: points depend
// only on (z, sv)). 2 rows per flagged channel. Probe 3 (needed only when
// e1<0 && e2<0) is done by the caller in a separate, usually-empty eval.
__device__ __forceinline__ void do_eval2(unsigned char* sm, int t, bool flag,
    float p1x, float p1y, float p1z,
    float p2x, float p2y, float p2z,
    int evalIdx, float& e1, float& e2, bool& usedSpec){
  const int lane = t & 63;
  int* cnt = (int*)(sm + CNTB);
  const unsigned long long bal = __ballot(flag);
  const int pc = __popcll(bal);
  int base = 0;
  if (pc){
    int old = 0;
    if (lane == 0) old = atomicAdd(&cnt[evalIdx], pc);
    base = __shfl(old, 0);
  }
  const int r = base + __popcll(bal & ((1ULL << lane) - 1ULL));
  if (flag && 2*r + 1 < 256){                    // guard vs overflow
    float* PX = (float*)(sm+PXB);
    float* PY = (float*)(sm+PYB);
    float* PZ = (float*)(sm+PZB);
    PX[2*r+0] = p1x; PY[2*r+0] = p1y; PZ[2*r+0] = p1z;
    PX[2*r+1] = p2x; PY[2*r+1] = p2y; PZ[2*r+1] = p2z;
  }
  __syncthreads();                               // points + counter visible
  const int total = cnt[evalIdx] * 2;            // uniform
  e1 = 0.f; e2 = 0.f;
  if (total == 0){ usedSpec = true; return; }    // no overshoot anywhere
  if (total > 256){ usedSpec = false; return; }  // rare: sequential fallback
  eval_blockN(sm, t, (total + 31) >> 5);
  usedSpec = true;
  if (flag){
    const float b3v = *((const float*)(sm+B3B));
    const float* S = (const float*)(sm+SDFB);
    e1 = S[2*r+0] + b3v;
    e2 = S[2*r+1] + b3v;
  }
}

__global__ __launch_bounds__(512, 2)
void trace_kernel(const float* __restrict__ rays_d, const float* __restrict__ rays_o,
                  const float* __restrict__ W1, const float* __restrict__ b1,
                  const float* __restrict__ W2, const float* __restrict__ b2,
                  const float* __restrict__ W3, const float* __restrict__ b3,
                  float* __restrict__ out)
{
  __shared__ __align__(16) unsigned char sm[LDSZ];
  const int t = threadIdx.x;

  // ---- ray loads first (global latency hides under W2 staging VALU)
  const bool own = (t < 256);
  const int chan = blockIdx.x * 256 + (t & 255);
  const int ray  = chan >> 1;
  const int c01  = chan & 1;
  const float sgn = c01 ? -1.0f : 1.0f;

  float dx=0, dy=0, dz=0, ox=0, oy=0, oz=0;
  if (own){
    dx = rays_d[ray*3+0]; dy = rays_d[ray*3+1]; dz = rays_d[ray*3+2];
    ox = rays_o[ray*3+0]; oy = rays_o[ray*3+1]; oz = rays_o[ray*3+2];
  }

  // ---- stage W2: 3-split bf16, B-fragment order, conflict-free b128 writes.
  for (int si = t; si < 2048; si += 512){
    const int k    = si & 127;
    const int joct = si >> 7;
    s16x8 vh, vm, vl;
#pragma unroll
    for (int jj = 0; jj < 8; ++jj){
      const float w = W2[(joct*8 + jj)*128 + k];   // coalesced over lanes (k)
      unsigned short uh, um, ul;
      split3(w, uh, um, ul);
      vh[jj] = (short)uh; vm[jj] = (short)um; vl[jj] = (short)ul;
    }
    const int ct = k >> 4, kb = joct >> 2;
    const int slot = ((joct & 3)*16 + (k & 15))*16;
    *(s16x8*)(sm + WB(0,ct,kb) + slot) = vh;
    *(s16x8*)(sm + WB(1,ct,kb) + slot) = vm;
    *(s16x8*)(sm + WB(2,ct,kb) + slot) = vl;
  }
  if (t < 128){
    ((float4*)(sm+T1B))[t] = make_float4(W1[t], W1[128+t], W1[256+t], b1[t]);
    ((float*)(sm+B2B))[t] = b2[t];
    ((float*)(sm+W3B))[t] = W3[t];
  }
  if (t == 0) *((float*)(sm+B3B)) = b3[0];
  if (t < 32) ((int*)(sm+CNTB))[t] = 0;          // rotating counters, once

  // ---- origin eval: channels of a ray share the SAME point (z=0) -> only
  // even channels evaluate; STATIC slots (t>>1); both siblings read directly.
  if (own && (c01 == 0)){
    const int slot = t >> 1;                     // 0..127
    ((float*)(sm+PXB))[slot] = ox;
    ((float*)(sm+PYB))[slot] = oy;
    ((float*)(sm+PZB))[slot] = oz;
  }
  __syncthreads();                               // staging + points visible
  eval_blockN(sm, t, 4);                         // 128 rows, ends w/ barrier
  float next_sdf = own
      ? ((const float*)(sm+SDFB))[(t & 255) >> 1] + *((const float*)(sm+B3B))
      : 0.f;

  float z = 0.f, sv = 0.f;
  float px = ox, py = oy, pz = oz;
  bool m = own;
  int evalIdx = 0;

  for (int it = 0; it < 6; ++it){
    sv = m ? next_sdf : 0.f;
    sv = (sv <= THRS) ? 0.f : sv;
    m = m && (sv > THRS);
    z = fmaf(sgn, sv, z);
    px = fmaf(z, dx, ox); py = fmaf(z, dy, oy); pz = fmaf(z, dz, oz);

    // step eval: only channels still marching
    next_sdf = do_eval(sm, t, m, px, py, pz, 0.f, evalIdx);

    bool fm = own && (next_sdf < 0.f);

    // ---- speculative fix probes 1+2 (oblivious given (z, sv)); same fmaf
    // chain as the sequential path -> bitwise-identical z values.
    const float z1p = fmaf(-0.5f  * sgn, sv, z);
    const float z2p = fmaf(-0.25f * sgn, sv, z1p);
    const float z3p = fmaf(-0.125f* sgn, sv, z2p);
    float e1, e2; bool usedSpec;
    do_eval2(sm, t, fm,
             fmaf(z1p,dx,ox), fmaf(z1p,dy,oy), fmaf(z1p,dz,oz),
             fmaf(z2p,dx,ox), fmaf(z2p,dy,oy), fmaf(z2p,dz,oz),
             evalIdx + 1, e1, e2, usedSpec);
    if (usedSpec){
      // probe 3 only for double-failures (usually none -> 2 barriers)
      const bool f3 = fm && (e1 < 0.f) && (e2 < 0.f);
      const float e3 = do_eval(sm, t, f3,
                               fmaf(z3p,dx,ox), fmaf(z3p,dy,oy),
                               fmaf(z3p,dz,oz), 0.f, evalIdx + 2);
      if (fm){
        if (e1 >= 0.f)      { z = z1p; next_sdf = e1; }
        else if (e2 >= 0.f) { z = z2p; next_sdf = e2; }
        else                { z = z3p; next_sdf = e3; }
        px = fmaf(z, dx, ox); py = fmaf(z, dy, oy); pz = fmaf(z, dz, oz);
      }
    } else {
      // sequential fallback (rare; bitwise-identical semantics)
      float step = 0.5f;
      for (int fi = 0; fi < 3; ++fi){
        if (fm){
          z = fmaf(-step*sgn, sv, z);
          px = fmaf(z, dx, ox); py = fmaf(z, dy, oy); pz = fmaf(z, dz, oz);
        }
        next_sdf = do_eval(sm, t, fm, px, py, pz, next_sdf, evalIdx + 2 + fi);
        fm = own && (next_sdf < 0.f);
        step *= 0.5f;
      }
    }
    evalIdx += 5;

    // cross-channel coupling: adjacent thread holds the sibling channel
    const float zo = __shfl_xor(z, 1);             // unconditional
    const bool pair = c01 ? (zo < z) : (z < zo);
    m = m && pair;

    // all-dead fixed-point: remaining iterations are exact no-ops
    if (!__syncthreads_or((int)m)) break;
  }

  if (own){
    // final top-of-loop mask update
    sv = m ? next_sdf : 0.f;
    sv = (sv <= THRS) ? 0.f : sv;
    m = m && (sv > THRS);

    // outputs: points (2,N,3), z (2,N), mask (2,N) flat
    const size_t pb = (size_t)c01 * NRAYS * 3 + (size_t)ray * 3;
    out[pb+0] = px; out[pb+1] = py; out[pb+2] = pz;
    out[2*NRAYS*3 + (size_t)c01*NRAYS + ray] = z;
    out[2*NRAYS*3 + 2*NRAYS + (size_t)c01*NRAYS + ray] = m ? 1.f : 0.f;
  }
}

extern "C" void kernel_launch(void* const* d_in, const int* in_sizes, int n_in,
                              void* d_out, int out_size, void* d_ws, size_t ws_size,
                              hipStream_t stream) {
  const float* rays_d = (const float*)d_in[0];
  const float* rays_o = (const float*)d_in[1];
  const float* W1 = (const float*)d_in[2];
  const float* b1 = (const float*)d_in[3];
  const float* W2 = (const float*)d_in[4];
  const float* b2 = (const float*)d_in[5];
  const float* W3 = (const float*)d_in[6];
  const float* b3 = (const float*)d_in[7];
  float* out = (float*)d_out;
  (void)d_ws; (void)ws_size;

  // 256 blocks x 512 threads; each block owns 256 ray-channels (1 block/CU)
  trace_kernel<<<256, 512, 0, stream>>>(
      rays_d, rays_o, W1, b1, W2, b2, W3, b3, out);
}